// Round 6
// baseline (363.131 us; speedup 1.0000x reference)
//
#include <hip/hip_runtime.h>
#include <hip/hip_bf16.h>

// LengthRegulator (FastSpeech): expanded gather + mel_len + mel_mask.
// Outputs concatenated flat in d_out as float32:
//   [0, B*max_len*D)                      expanded
//   [B*max_len*D, +B)                     mel_len (as float)
//   [B*max_len*D + B, +B*max_len)         mel_mask (0.0 / 1.0)
//
// R5 -> R6: token-major scatter (32k blocks, dur-imbalanced 2-18KB bursts)
// replaced by balanced frame-range writer: 2048 blocks (8/CU), each owns
// ~F contiguous frames (~148KB store stream), csum staged in LDS, one
// binary search per half-block, current row cached in registers across
// its ~4.5-frame reuse. NT stores for the big streams (R4 best config).

#define S_TOK 1024  // tokens per sequence
#define B_SZ  32    // batch
#define NBX   64    // frame-range blocks per batch (64 x 32 = 2048 = 8/CU)

typedef float vfloat4 __attribute__((ext_vector_type(4)));

// One wave per batch: 16 durations/lane serial prefix + wave shuffle scan.
__global__ __launch_bounds__(64)
void lr_scan_kernel(const int* __restrict__ dur,
                    int* __restrict__ csum,
                    float* __restrict__ mel_len_out) {
    const int b = blockIdx.x;
    const int lane = threadIdx.x;
    const int* __restrict__ d = dur + b * S_TOK;

    int v[16];
    int sum = 0;
#pragma unroll
    for (int k = 0; k < 16; ++k) {
        v[k] = d[lane * 16 + k];
        sum += v[k];
    }
    int run = 0;
#pragma unroll
    for (int k = 0; k < 16; ++k) { run += v[k]; v[k] = run; }

    int tot = sum;
#pragma unroll
    for (int off = 1; off < 64; off <<= 1) {
        int n = __shfl_up(tot, off, 64);
        if (lane >= off) tot += n;
    }
    const int excl = tot - sum;

#pragma unroll
    for (int k = 0; k < 16; ++k)
        csum[b * S_TOK + lane * 16 + k] = v[k] + excl;
    if (lane == 63) mel_len_out[b] = (float)tot;
}

// Balanced frame-range writer. Block (bx, b) owns frames [bx*F, bx*F+F).
// Two 128-thread halves take contiguous sub-ranges. csum in LDS; current
// source row cached in registers; NT stores for expanded frames.
__global__ __launch_bounds__(256)
void lr_write_kernel(const float* __restrict__ x,
                     const int* __restrict__ csum,
                     float* __restrict__ out,
                     float* __restrict__ mask,
                     int D, int max_len) {
    const int b = blockIdx.y;
    const int tid = threadIdx.x;
    const int half = tid >> 7;   // wave-uniform
    const int lane = tid & 127;

    __shared__ __align__(16) int cs[S_TOK];
    ((int4*)cs)[tid] = ((const int4*)(csum + b * S_TOK))[tid];  // 256*16B = 4KB
    __syncthreads();
    const int mel = cs[S_TOK - 1];

    const int F = (max_len + NBX - 1) / NBX;
    const int t0 = blockIdx.x * F;
    const int tEnd = min(t0 + F, max_len);
    const int hF = (F + 1) >> 1;
    int t = min(t0 + half * hF, max_len);
    const int tend = min(t0 + (half ? F : hF), max_len);

    const float* __restrict__ xb = x + (size_t)b * S_TOK * (size_t)D;
    float* __restrict__ ob = out + (size_t)b * max_len * (size_t)D;

    const int dataEnd = min(tend, mel);

    if (t < dataEnd) {
        // first s with cs[s] > t (t < mel = cs[S-1] so s < S_TOK)
        int lo = 0, hi = S_TOK;
        while (lo < hi) {
            int mid = (lo + hi) >> 1;
            if (cs[mid] > t) hi = mid; else lo = mid + 1;
        }
        int s = lo;
        vfloat4 v = ((const vfloat4*)(xb + (size_t)s * D))[lane];
        int cur = s;
        for (; t < dataEnd; ++t) {
            while (cs[s] <= t) ++s;               // amortized walk in LDS
            if (s != cur) {
                v = ((const vfloat4*)(xb + (size_t)s * D))[lane];
                cur = s;
            }
            __builtin_nontemporal_store(v, (vfloat4*)(ob + (size_t)t * D) + lane);
        }
    }
    const vfloat4 z = (vfloat4)(0.f);
    for (; t < tend; ++t)
        __builtin_nontemporal_store(z, (vfloat4*)(ob + (size_t)t * D) + lane);

    // mask for the whole block range
    float* __restrict__ mb = mask + (size_t)b * max_len;
    for (int u = t0 + tid; u < tEnd; u += 256)
        mb[u] = (u >= mel) ? 1.0f : 0.0f;
}

extern "C" void kernel_launch(void* const* d_in, const int* in_sizes, int n_in,
                              void* d_out, int out_size, void* d_ws, size_t ws_size,
                              hipStream_t stream) {
    const float* x = (const float*)d_in[0];
    const int* dur = (const int*)d_in[1];
    float* out = (float*)d_out;

    const int D = in_sizes[0] / in_sizes[1];                 // 512
    const int max_len = (out_size / B_SZ - 1) / (D + 1);     // data-dependent, from out_size

    int* csum = (int*)d_ws;                                  // B*S ints = 128 KB
    float* mel_len = out + (size_t)B_SZ * max_len * D;
    float* mask = mel_len + B_SZ;

    lr_scan_kernel<<<B_SZ, 64, 0, stream>>>(dur, csum, mel_len);

    dim3 grid(NBX, B_SZ);
    lr_write_kernel<<<grid, 256, 0, stream>>>(x, csum, out, mask, D, max_len);
}

// Round 7
// 359.724 us; speedup vs baseline: 1.0095x; 1.0095x over previous
//
#include <hip/hip_runtime.h>
#include <hip/hip_bf16.h>

// LengthRegulator (FastSpeech): expanded gather + mel_len + mel_mask.
// Outputs concatenated flat in d_out as float32:
//   [0, B*max_len*D)                      expanded
//   [B*max_len*D, +B)                     mel_len (as float)
//   [B*max_len*D + B, +B*max_len)         mel_mask (0.0 / 1.0)
//
// R6 -> R7: pure-streaming writer. Block = 16-token chunk: stage 32KB of x
// contiguously into LDS (independent coalesced loads, all misses in flight),
// build frame->row map (dur<=8 so span<=128), then the store loop is only
// LDS-read -> NT-store. Tail zeros + mask split evenly across the 64 blocks
// per batch (no straggler). No dependent global loads in the hot loop.

#define S_TOK 1024         // tokens per sequence
#define B_SZ  32           // batch
#define D_DIM 512          // feature dim (fixed by problem)
#define TPB   16           // tokens per block
#define NBX   (S_TOK/TPB)  // 64 chunk-blocks per batch

typedef float vfloat4 __attribute__((ext_vector_type(4)));

// One wave per batch: 16 durations/lane serial prefix + wave shuffle scan.
__global__ __launch_bounds__(64)
void lr_scan_kernel(const int* __restrict__ dur,
                    int* __restrict__ csum,
                    float* __restrict__ mel_len_out) {
    const int b = blockIdx.x;
    const int lane = threadIdx.x;
    const int* __restrict__ d = dur + b * S_TOK;

    int v[16];
    int sum = 0;
#pragma unroll
    for (int k = 0; k < 16; ++k) {
        v[k] = d[lane * 16 + k];
        sum += v[k];
    }
    int run = 0;
#pragma unroll
    for (int k = 0; k < 16; ++k) { run += v[k]; v[k] = run; }

    int tot = sum;
#pragma unroll
    for (int off = 1; off < 64; off <<= 1) {
        int n = __shfl_up(tot, off, 64);
        if (lane >= off) tot += n;
    }
    const int excl = tot - sum;

#pragma unroll
    for (int k = 0; k < 16; ++k)
        csum[b * S_TOK + lane * 16 + k] = v[k] + excl;
    if (lane == 63) mel_len_out[b] = (float)tot;
}

// Streaming writer: block (j, b) owns tokens [16j, 16j+16) -> frames
// [c[16j-1], c[16j+15]) (contiguous partition of [0, mel)). Also zeros its
// 1/64 share of the tail [mel, max_len) and writes its 1/64 of the mask.
__global__ __launch_bounds__(256)
void lr_write_kernel(const float* __restrict__ x,
                     const int* __restrict__ csum,
                     float* __restrict__ out,
                     float* __restrict__ mask,
                     int max_len) {
    const int b = blockIdx.y;
    const int j = blockIdx.x;
    const int tid = threadIdx.x;
    const int s0 = j * TPB;

    __shared__ __align__(16) float rows[TPB * D_DIM];   // 32 KB
    __shared__ int cval[TPB + 1];
    __shared__ unsigned char map[TPB * 8];              // span <= 128 (dur<=8)
    __shared__ int smel;

    const int* __restrict__ cb = csum + b * S_TOK;
    if (tid <= TPB) {
        const int s = s0 - 1 + tid;
        cval[tid] = (s < 0) ? 0 : cb[s];
    }
    if (tid == 255) smel = cb[S_TOK - 1];

    // Stage 16 contiguous rows (32 KB) of x into LDS: 8 independent
    // coalesced float4 loads per thread — all misses issued together.
    {
        const float4* __restrict__ src4 =
            (const float4*)(x + ((size_t)b * S_TOK + s0) * D_DIM);
        float4* __restrict__ dst4 = (float4*)rows;
#pragma unroll
        for (int k = 0; k < 8; ++k)
            dst4[tid + k * 256] = src4[tid + k * 256];
    }
    __syncthreads();

    // frame -> row map (threads 0..15, disjoint ranges, <=8 iters each)
    const int fBase = cval[0];
    const int fEnd = cval[TPB];
    if (tid < TPB) {
        const int lo = cval[tid], hi = cval[tid + 1];
        for (int t = lo; t < hi; ++t) map[t - fBase] = (unsigned char)tid;
    }
    __syncthreads();

    const int mel = smel;
    const int half = tid >> 7;       // wave-uniform
    const int lane = tid & 127;
    float* __restrict__ ob = out + (size_t)b * max_len * D_DIM;

    // main span: each half writes a contiguous sub-span
    {
        const int span = fEnd - fBase;
        const int hspan = (span + 1) >> 1;
        int t = fBase + half * hspan;
        const int tend = fBase + min(span, (half ? span : hspan));
        for (; t < tend; ++t) {
            const int r = map[t - fBase];   // LDS broadcast
            const vfloat4 v = ((const vfloat4*)(rows + r * D_DIM))[lane];
            __builtin_nontemporal_store(v, (vfloat4*)(ob + (size_t)t * D_DIM) + lane);
        }
    }

    // tail zeros: even 1/64 share of [mel, max_len)
    const int tail = max_len - mel;
    if (tail > 0) {
        const int chunk = (tail + NBX - 1) / NBX;
        const int z0 = mel + j * chunk;
        const int z1 = min(z0 + chunk, max_len);
        if (z0 < z1) {
            const int zn = z1 - z0;
            const int hz = (zn + 1) >> 1;
            int zt = z0 + half * hz;
            const int zend = z0 + min(zn, (half ? zn : hz));
            const vfloat4 zero = (vfloat4)(0.f);
            for (; zt < zend; ++zt)
                __builtin_nontemporal_store(zero, (vfloat4*)(ob + (size_t)zt * D_DIM) + lane);
        }
    }

    // mask: even 1/64 share of [0, max_len)
    {
        const int seg = (max_len + NBX - 1) / NBX;
        const int m0 = j * seg;
        const int m1 = min(m0 + seg, max_len);
        float* __restrict__ mb = mask + (size_t)b * max_len;
        for (int u = m0 + tid; u < m1; u += 256)
            mb[u] = (u >= mel) ? 1.0f : 0.0f;
    }
}

extern "C" void kernel_launch(void* const* d_in, const int* in_sizes, int n_in,
                              void* d_out, int out_size, void* d_ws, size_t ws_size,
                              hipStream_t stream) {
    const float* x = (const float*)d_in[0];
    const int* dur = (const int*)d_in[1];
    float* out = (float*)d_out;

    const int D = in_sizes[0] / in_sizes[1];                 // 512
    const int max_len = (out_size / B_SZ - 1) / (D + 1);     // data-dependent, from out_size

    int* csum = (int*)d_ws;                                  // B*S ints = 128 KB
    float* mel_len = out + (size_t)B_SZ * max_len * D;
    float* mask = mel_len + B_SZ;

    lr_scan_kernel<<<B_SZ, 64, 0, stream>>>(dur, csum, mel_len);

    dim3 grid(NBX, B_SZ);
    lr_write_kernel<<<grid, 256, 0, stream>>>(x, csum, out, mask, max_len);
}